// Round 15
// baseline (420.005 us; speedup 1.0000x reference)
//
#include <hip/hip_runtime.h>
#include <math.h>

#define D_ 256
#define NL_ 4
#define NC_ 2
#define L_LEN 1024
#define NSTATE_ 64
#define DIN_ 512
#define H_ 8
#define P_ 64
#define CONVDIM_ 640
#define DPROJ_ 1160
#define EPS_ 1e-5f
#define NCH_ 16

typedef __attribute__((ext_vector_type(8))) short short8;
typedef __attribute__((ext_vector_type(4))) float f32x4;
typedef __attribute__((ext_vector_type(4))) unsigned short us4;

__device__ __forceinline__ float siluf(float x) { return x / (1.f + __expf(-x)); }
__device__ __forceinline__ float geluf(float x) { return 0.5f * x * (1.f + erff(x * 0.70710678118654752f)); }
__device__ __forceinline__ unsigned short f2bf(float f) {
    unsigned u = __float_as_uint(f);
    u += 0x7FFFu + ((u >> 16) & 1u);
    return (unsigned short)(u >> 16);
}
__device__ __forceinline__ float bf2f(unsigned short h) {
    return __uint_as_float(((unsigned)h) << 16);
}

// x[b,l,d] = emb[ids[b,l], d] + pos[l, d]
__global__ void k_embed(const int* __restrict__ ids, const float* __restrict__ emb,
                        const float* __restrict__ pos, float* __restrict__ x, int total) {
    int i = blockIdx.x * blockDim.x + threadIdx.x;
    if (i >= total) return;
    int d = i & (D_ - 1);
    int bl = i >> 8;
    int l = bl & (L_LEN - 1);
    x[i] = emb[ids[bl] * D_ + d] + pos[l * D_ + d];
}

// split Win and (Wout * nw) into bf16 hi/lo planes
__global__ void k_w2bf2(const float* __restrict__ Wi, const float* __restrict__ Wo,
                        const float* __restrict__ nw,
                        unsigned short* __restrict__ wih, unsigned short* __restrict__ wil,
                        unsigned short* __restrict__ woh, unsigned short* __restrict__ wol,
                        int nin, int ntot) {
    int i = blockIdx.x * blockDim.x + threadIdx.x;
    if (i >= ntot) return;
    if (i < nin) {
        float f = Wi[i];
        unsigned short h = f2bf(f);
        wih[i] = h;
        wil[i] = f2bf(f - bf2f(h));
    } else {
        int j = i - nin;
        int layer = j / (D_ * DIN_);
        int k = j % DIN_;
        float f = Wo[j] * nw[layer * DIN_ + k];
        unsigned short h = f2bf(f);
        woh[j] = h;
        wol[j] = f2bf(f - bf2f(h));
    }
}

// in-proj: zx[M,N] = x[M,K] @ Win^T; A f32 (split inline), B pre-split bf16.
// BM=64, BN=64, BK=32; grid (19, 32); 256 threads (4 waves x 16-row tile).
__global__ void __launch_bounds__(256) gemm_in(const float* __restrict__ A,
        const unsigned short* __restrict__ Bhi, const unsigned short* __restrict__ Blo,
        float* __restrict__ C, int M, int N, int K) {
    __shared__ __align__(16) unsigned short Ah[64 * 40];
    __shared__ __align__(16) unsigned short Al[64 * 40];
    __shared__ __align__(16) unsigned short Bh[64 * 40];
    __shared__ __align__(16) unsigned short Bl[64 * 40];
    const int tid = threadIdx.x;
    const int col0 = blockIdx.x * 64;
    const int row0 = blockIdx.y * 64;

    const int sar = tid >> 2, sas = (tid & 3) * 8;
    const bool bok = (col0 + sar) < N;
    const float* aptr = A + (size_t)(row0 + sar) * K + sas;
    const unsigned short* bhptr = Bhi + (size_t)(col0 + sar) * K + sas;
    const unsigned short* blptr = Blo + (size_t)(col0 + sar) * K + sas;

    float4 pa0 = *(const float4*)aptr;
    float4 pa1 = *(const float4*)(aptr + 4);
    short8 pbh = {0, 0, 0, 0, 0, 0, 0, 0}, pbl = {0, 0, 0, 0, 0, 0, 0, 0};
    if (bok) {
        pbh = *(const short8*)bhptr;
        pbl = *(const short8*)blptr;
    }

    const int wave = tid >> 6, lane = tid & 63;
    const int lq = lane >> 4, lm = lane & 15;
    f32x4 acc[4] = {};
    const int nsteps = K >> 5;
    for (int s = 0; s < nsteps; ++s) {
        __syncthreads();
        {
            float4 f = pa0;
            unsigned short h0 = f2bf(f.x), h1 = f2bf(f.y), h2 = f2bf(f.z), h3 = f2bf(f.w);
            us4 hv = {h0, h1, h2, h3};
            us4 lv = {f2bf(f.x - bf2f(h0)), f2bf(f.y - bf2f(h1)),
                      f2bf(f.z - bf2f(h2)), f2bf(f.w - bf2f(h3))};
            *(us4*)&Ah[sar * 40 + sas] = hv;
            *(us4*)&Al[sar * 40 + sas] = lv;
            f = pa1;
            h0 = f2bf(f.x); h1 = f2bf(f.y); h2 = f2bf(f.z); h3 = f2bf(f.w);
            us4 hv2 = {h0, h1, h2, h3};
            us4 lv2 = {f2bf(f.x - bf2f(h0)), f2bf(f.y - bf2f(h1)),
                       f2bf(f.z - bf2f(h2)), f2bf(f.w - bf2f(h3))};
            *(us4*)&Ah[sar * 40 + sas + 4] = hv2;
            *(us4*)&Al[sar * 40 + sas + 4] = lv2;
        }
        *(short8*)&Bh[sar * 40 + sas] = pbh;
        *(short8*)&Bl[sar * 40 + sas] = pbl;
        __syncthreads();
        if (s + 1 < nsteps) {
            int ko = (s + 1) * 32;
            pa0 = *(const float4*)(aptr + ko);
            pa1 = *(const float4*)(aptr + ko + 4);
            if (bok) {
                pbh = *(const short8*)(bhptr + ko);
                pbl = *(const short8*)(blptr + ko);
            }
        }
        short8 ah = *(const short8*)&Ah[(wave * 16 + lm) * 40 + lq * 8];
        short8 al = *(const short8*)&Al[(wave * 16 + lm) * 40 + lq * 8];
#pragma unroll
        for (int ct = 0; ct < 4; ++ct) {
            short8 bh = *(const short8*)&Bh[(ct * 16 + lm) * 40 + lq * 8];
            short8 bl = *(const short8*)&Bl[(ct * 16 + lm) * 40 + lq * 8];
            acc[ct] = __builtin_amdgcn_mfma_f32_16x16x32_bf16(ah, bh, acc[ct], 0, 0, 0);
            acc[ct] = __builtin_amdgcn_mfma_f32_16x16x32_bf16(ah, bl, acc[ct], 0, 0, 0);
            acc[ct] = __builtin_amdgcn_mfma_f32_16x16x32_bf16(al, bh, acc[ct], 0, 0, 0);
        }
    }
#pragma unroll
    for (int ct = 0; ct < 4; ++ct) {
        int col = col0 + ct * 16 + lm;
        if (col >= N) continue;
        int rbase = row0 + wave * 16 + lq * 4;
#pragma unroll
        for (int reg = 0; reg < 4; ++reg) {
            C[(size_t)(rbase + reg) * N + col] = acc[ct][reg];
        }
    }
}

// out-proj: x[m][n] += sc[m] * sum_k g[m][k]*(W*nw)[n][k]; split-K 8 (kchunk=64).
// grid (4, 16, 8): BN=64, BM=128.
__global__ void __launch_bounds__(256) gemm_outs(const unsigned short* __restrict__ Ghg,
        const unsigned short* __restrict__ Glg, const float* __restrict__ rowssq,
        const unsigned short* __restrict__ Bhi, const unsigned short* __restrict__ Blo,
        float* __restrict__ x) {
    __shared__ __align__(16) unsigned short Ah[128 * 40];
    __shared__ __align__(16) unsigned short Al[128 * 40];
    __shared__ __align__(16) unsigned short Bh[64 * 40];
    __shared__ __align__(16) unsigned short Bl[64 * 40];
    const int tid = threadIdx.x;
    const int col0 = blockIdx.x * 64;
    const int row0 = blockIdx.y * 128;
    const int kbase = blockIdx.z * 64;
    const int sar = tid >> 1, sas = (tid & 1) * 16;
    const int sbr = tid >> 2, sbs = (tid & 3) * 8;
    const unsigned short* ahptr = Ghg + (size_t)(row0 + sar) * DIN_ + kbase + sas;
    const unsigned short* alptr = Glg + (size_t)(row0 + sar) * DIN_ + kbase + sas;
    const unsigned short* bhptr = Bhi + (size_t)(col0 + sbr) * DIN_ + kbase + sbs;
    const unsigned short* blptr = Blo + (size_t)(col0 + sbr) * DIN_ + kbase + sbs;

    short8 pah0 = *(const short8*)ahptr, pah1 = *(const short8*)(ahptr + 8);
    short8 pal0 = *(const short8*)alptr, pal1 = *(const short8*)(alptr + 8);
    short8 pbh = *(const short8*)bhptr, pbl = *(const short8*)blptr;

    const int wave = tid >> 6, lane = tid & 63;
    const int lq = lane >> 4, lm = lane & 15;
    f32x4 acc[2][4] = {};
    for (int s = 0; s < 2; ++s) {
        __syncthreads();
        *(short8*)&Ah[sar * 40 + sas] = pah0;
        *(short8*)&Ah[sar * 40 + sas + 8] = pah1;
        *(short8*)&Al[sar * 40 + sas] = pal0;
        *(short8*)&Al[sar * 40 + sas + 8] = pal1;
        *(short8*)&Bh[sbr * 40 + sbs] = pbh;
        *(short8*)&Bl[sbr * 40 + sbs] = pbl;
        __syncthreads();
        if (s + 1 < 2) {
            int ko = 32;
            pah0 = *(const short8*)(ahptr + ko);
            pah1 = *(const short8*)(ahptr + ko + 8);
            pal0 = *(const short8*)(alptr + ko);
            pal1 = *(const short8*)(alptr + ko + 8);
            pbh = *(const short8*)(bhptr + ko);
            pbl = *(const short8*)(blptr + ko);
        }
        short8 bh[4], bl[4];
#pragma unroll
        for (int ct = 0; ct < 4; ++ct) {
            bh[ct] = *(const short8*)&Bh[(ct * 16 + lm) * 40 + lq * 8];
            bl[ct] = *(const short8*)&Bl[(ct * 16 + lm) * 40 + lq * 8];
        }
#pragma unroll
        for (int rt = 0; rt < 2; ++rt) {
            short8 ah = *(const short8*)&Ah[(wave * 32 + rt * 16 + lm) * 40 + lq * 8];
            short8 al = *(const short8*)&Al[(wave * 32 + rt * 16 + lm) * 40 + lq * 8];
#pragma unroll
            for (int ct = 0; ct < 4; ++ct) {
                acc[rt][ct] = __builtin_amdgcn_mfma_f32_16x16x32_bf16(ah, bh[ct], acc[rt][ct], 0, 0, 0);
                acc[rt][ct] = __builtin_amdgcn_mfma_f32_16x16x32_bf16(ah, bl[ct], acc[rt][ct], 0, 0, 0);
                acc[rt][ct] = __builtin_amdgcn_mfma_f32_16x16x32_bf16(al, bh[ct], acc[rt][ct], 0, 0, 0);
            }
        }
    }
#pragma unroll
    for (int rt = 0; rt < 2; ++rt) {
        int rbase = row0 + wave * 32 + rt * 16 + lq * 4;
        float sc[4];
#pragma unroll
        for (int reg = 0; reg < 4; ++reg)
            sc[reg] = rsqrtf(rowssq[rbase + reg] * (1.f / DIN_) + EPS_);
#pragma unroll
        for (int ct = 0; ct < 4; ++ct) {
            int col = col0 + ct * 16 + lm;
#pragma unroll
            for (int reg = 0; reg < 4; ++reg) {
                atomicAdd(&x[(size_t)(rbase + reg) * D_ + col], sc[reg] * acc[rt][ct][reg]);
            }
        }
    }
}

// Fused SSM (256-thread, 4x4 micro); parallel shuffle scan for cumsum; zeroes rowssq.
__global__ void __launch_bounds__(256) k_ssmA(const float* __restrict__ zx,
        const float* __restrict__ cw, const float* __restrict__ cb,
        const float* __restrict__ dtbias, const float* __restrict__ Alog,
        const float* __restrict__ Dp,
        float* __restrict__ Sbuf, float* __restrict__ decay,
        float* __restrict__ Ctil, float* __restrict__ y, float* __restrict__ rowssq) {
    __shared__ float U[64][65];
    __shared__ float V[64][65];
    __shared__ float W[64][65];
    __shared__ float sdt[64], cs[64], wj[64];
    const int c = blockIdx.x, bh = blockIdx.y;
    const int b = bh >> 3, h = bh & 7;
    const int l0 = c << 6;
    const int tid = threadIdx.x, wid = tid >> 6, lane = tid & 63;

    if (h == 0 && tid < 64) rowssq[b * L_LEN + l0 + tid] = 0.f;

    const int chx = h * P_ + lane;
    const int chb = DIN_ + lane;
    const int chc = DIN_ + NSTATE_ + lane;
    float wx0 = cw[chx * 4], wx1 = cw[chx * 4 + 1], wx2 = cw[chx * 4 + 2], wx3 = cw[chx * 4 + 3];
    float wb0 = cw[chb * 4], wb1 = cw[chb * 4 + 1], wb2 = cw[chb * 4 + 2], wb3 = cw[chb * 4 + 3];
    float wc0 = cw[chc * 4], wc1 = cw[chc * 4 + 1], wc2 = cw[chc * 4 + 2], wc3 = cw[chc * 4 + 3];
    float bx = cb[chx], bb = cb[chb], bc = cb[chc];

    for (int r = 0; r < 64; r += 4) {
        int j = r + wid;
        int l = l0 + j;
        float ax = bx, ab = bb, ac = bc;
#pragma unroll
        for (int k = 0; k < 4; ++k) {
            int t = l - 3 + k;
            if (t >= 0) {
                const float* row = zx + (size_t)(b * L_LEN + t) * DPROJ_;
                float wxk = (k == 0) ? wx0 : (k == 1) ? wx1 : (k == 2) ? wx2 : wx3;
                float wbk = (k == 0) ? wb0 : (k == 1) ? wb1 : (k == 2) ? wb2 : wb3;
                float wck = (k == 0) ? wc0 : (k == 1) ? wc1 : (k == 2) ? wc2 : wc3;
                ax += wxk * row[DIN_ + chx];
                ab += wbk * row[DIN_ + chb];
                ac += wck * row[DIN_ + chc];
            }
        }
        U[j][lane] = siluf(ax);
        V[j][lane] = siluf(ab);
        W[j][lane] = siluf(ac);
    }
    if (tid < 64) {
        float xv = zx[(size_t)(b * L_LEN + l0 + tid) * DPROJ_ + (DPROJ_ - H_) + h] + dtbias[h];
        float sp = fmaxf(xv, 0.f) + log1pf(__expf(-fabsf(xv)));
        sdt[tid] = sp;
        float v = sp * (-__expf(Alog[h]));
#pragma unroll
        for (int off = 1; off < 64; off <<= 1) {
            float t = __shfl_up(v, off, 64);
            if (tid >= off) v += t;
        }
        cs[tid] = v;
        float tot = __shfl(v, 63, 64);
        wj[tid] = __expf(tot - v) * sp;
        if (tid == 63) decay[bh * NCH_ + c] = __expf(tot);
    }
    __syncthreads();

    const int t4 = (tid & 15) * 4;
    const int r4 = (tid >> 4) * 4;
    const size_t sbase = (size_t)(bh * NCH_ + c) * 4096;

    {
        float acc[4][4] = {};
        for (int j = 0; j < 64; ++j) {
            float w = wj[j];
            float4 xv = *(const float4*)&U[j][r4];
            float4 bv = *(const float4*)&V[j][t4];
            float xw[4] = {xv.x * w, xv.y * w, xv.z * w, xv.w * w};
#pragma unroll
            for (int ii = 0; ii < 4; ++ii) {
                acc[ii][0] += xw[ii] * bv.x;
                acc[ii][1] += xw[ii] * bv.y;
                acc[ii][2] += xw[ii] * bv.z;
                acc[ii][3] += xw[ii] * bv.w;
            }
        }
#pragma unroll
        for (int ii = 0; ii < 4; ++ii) {
            float4 v = {acc[ii][0], acc[ii][1], acc[ii][2], acc[ii][3]};
            *(float4*)&Sbuf[sbase + (size_t)(r4 + ii) * 64 + t4] = v;
        }
    }
    for (int r = 0; r < 64; r += 4) {
        int ii = r + wid;
        Ctil[sbase + ii * 64 + lane] = __expf(cs[ii]) * W[ii][lane];
    }
    float g[4][4] = {};
    for (int ng = 0; ng < 64; ng += 4) {
        float4 cf[4], bf[4];
#pragma unroll
        for (int ii = 0; ii < 4; ++ii) cf[ii] = *(const float4*)&W[r4 + ii][ng];
#pragma unroll
        for (int jj = 0; jj < 4; ++jj) bf[jj] = *(const float4*)&V[t4 + jj][ng];
#pragma unroll
        for (int ii = 0; ii < 4; ++ii)
#pragma unroll
            for (int jj = 0; jj < 4; ++jj)
                g[ii][jj] += cf[ii].x * bf[jj].x + cf[ii].y * bf[jj].y +
                             cf[ii].z * bf[jj].z + cf[ii].w * bf[jj].w;
    }
    float wt[4][4];
#pragma unroll
    for (int ii = 0; ii < 4; ++ii) {
        int i = r4 + ii;
        float csi = cs[i];
#pragma unroll
        for (int jj = 0; jj < 4; ++jj) {
            int j = t4 + jj;
            wt[ii][jj] = (j <= i) ? __expf(fminf(csi - cs[j], 0.f)) * sdt[j] * g[ii][jj] : 0.f;
        }
    }
    __syncthreads();
#pragma unroll
    for (int jj = 0; jj < 4; ++jj) {
        float4 v = {wt[0][jj], wt[1][jj], wt[2][jj], wt[3][jj]};
        *(float4*)&V[t4 + jj][r4] = v;
    }
    __syncthreads();
    {
        float acc[4][4] = {};
        for (int j = 0; j < 64; ++j) {
            float4 wv = *(const float4*)&V[j][r4];
            float4 xv = *(const float4*)&U[j][t4];
            float ws[4] = {wv.x, wv.y, wv.z, wv.w};
#pragma unroll
            for (int ii = 0; ii < 4; ++ii) {
                acc[ii][0] += ws[ii] * xv.x;
                acc[ii][1] += ws[ii] * xv.y;
                acc[ii][2] += ws[ii] * xv.z;
                acc[ii][3] += ws[ii] * xv.w;
            }
        }
        float Dh = Dp[h];
#pragma unroll
        for (int ii = 0; ii < 4; ++ii) {
            float4 xv = *(const float4*)&U[r4 + ii][t4];
            float4 v = {acc[ii][0] + Dh * xv.x, acc[ii][1] + Dh * xv.y,
                        acc[ii][2] + Dh * xv.z, acc[ii][3] + Dh * xv.w};
            *(float4*)&y[(size_t)(b * L_LEN + l0 + r4 + ii) * DIN_ + h * P_ + t4] = v;
        }
    }
}

// inter-chunk + prefix scan + gating; emits gated bf16 hi/lo planes + rowssq.
__global__ void __launch_bounds__(256) k_inter(const float* __restrict__ Sbuf,
        const float* __restrict__ Ctil, const float* __restrict__ decay,
        const float* __restrict__ zx, const float* __restrict__ y,
        unsigned short* __restrict__ gh, unsigned short* __restrict__ gl,
        float* __restrict__ rowssq) {
    __shared__ float Sm[64][65];
    __shared__ float Cm[64][65];
    const int c = blockIdx.x, bh = blockIdx.y;
    const int b = bh >> 3, h = bh & 7;
    const int l0 = c << 6;
    const int tid = threadIdx.x, wid = tid >> 6, lane = tid & 63;
    const size_t bhbase = (size_t)bh * NCH_ * 4096;

    float dec[NCH_];
#pragma unroll
    for (int k = 0; k < NCH_; ++k) dec[k] = decay[bh * NCH_ + k];

    float acc16[16] = {};
    float wgt = 1.f;
    for (int cp = c - 1; cp >= 0; --cp) {
        const float* src = Sbuf + bhbase + (size_t)cp * 4096;
#pragma unroll
        for (int i = 0; i < 16; ++i) acc16[i] += wgt * src[i * 256 + tid];
        wgt *= dec[cp];
    }
#pragma unroll
    for (int i = 0; i < 16; ++i) Sm[i * 4 + wid][lane] = acc16[i];

    const size_t base = bhbase + (size_t)c * 4096;
    for (int r = 0; r < 64; r += 4) {
        int pp = r + wid;
        Cm[pp][lane] = Ctil[base + pp * 64 + lane];
    }
    __syncthreads();
    const int t4 = (tid & 15) * 4;
    const int r4 = (tid >> 4) * 4;
    float acc[4][4] = {};
    if (c > 0) {
        for (int ng = 0; ng < 64; ng += 4) {
            float4 cf[4], sf[4];
#pragma unroll
            for (int ii = 0; ii < 4; ++ii) cf[ii] = *(const float4*)&Cm[r4 + ii][ng];
#pragma unroll
            for (int pp = 0; pp < 4; ++pp) sf[pp] = *(const float4*)&Sm[t4 + pp][ng];
#pragma unroll
            for (int ii = 0; ii < 4; ++ii)
#pragma unroll
                for (int pp = 0; pp < 4; ++pp)
                    acc[ii][pp] += cf[ii].x * sf[pp].x + cf[ii].y * sf[pp].y +
                                   cf[ii].z * sf[pp].z + cf[ii].w * sf[pp].w;
        }
    }
    float ssq[4];
#pragma unroll
    for (int ii = 0; ii < 4; ++ii) {
        int row = b * L_LEN + l0 + r4 + ii;
        const float* yr = &y[(size_t)row * DIN_ + h * P_ + t4];
        const float* zr = &zx[(size_t)row * DPROJ_ + h * P_ + t4];
        float4 v = *(const float4*)yr;
        float4 z = *(const float4*)zr;
        v.x = (v.x + acc[ii][0]) * siluf(z.x);
        v.y = (v.y + acc[ii][1]) * siluf(z.y);
        v.z = (v.z + acc[ii][2]) * siluf(z.z);
        v.w = (v.w + acc[ii][3]) * siluf(z.w);
        unsigned short h0 = f2bf(v.x), h1 = f2bf(v.y), h2 = f2bf(v.z), h3 = f2bf(v.w);
        us4 hv = {h0, h1, h2, h3};
        us4 lv = {f2bf(v.x - bf2f(h0)), f2bf(v.y - bf2f(h1)),
                  f2bf(v.z - bf2f(h2)), f2bf(v.w - bf2f(h3))};
        *(us4*)&gh[(size_t)row * DIN_ + h * P_ + t4] = hv;
        *(us4*)&gl[(size_t)row * DIN_ + h * P_ + t4] = lv;
        ssq[ii] = v.x * v.x + v.y * v.y + v.z * v.z + v.w * v.w;
    }
#pragma unroll
    for (int o = 1; o < 16; o <<= 1) {
#pragma unroll
        for (int ii = 0; ii < 4; ++ii) ssq[ii] += __shfl_xor(ssq[ii], o, 64);
    }
    if ((tid & 15) == 0) {
#pragma unroll
        for (int ii = 0; ii < 4; ++ii)
            atomicAdd(&rowssq[b * L_LEN + l0 + r4 + ii], ssq[ii]);
    }
}

// pooling + classifier head, one block per batch, 1024 threads
__global__ void __launch_bounds__(1024) k_poolhead(const float* __restrict__ x,
                           const float* __restrict__ pw, const float* __restrict__ pb,
                           const float* __restrict__ c1w, const float* __restrict__ c1b,
                           const float* __restrict__ c2w, const float* __restrict__ c2b,
                           float* __restrict__ out) {
    __shared__ float ps[4][256], pm[4][256];
    __shared__ float sp[256], s1[256], s2[128];
    int b = blockIdx.x, tid = threadIdx.x;
    int t = tid & 255, grp = tid >> 8;
    const float* xb = x + (size_t)b * L_LEN * D_ + (size_t)grp * 256 * D_ + t;
    float s = 0.f, m = -INFINITY;
    for (int l = 0; l < 256; l += 4) {
        float v0 = xb[(size_t)l * D_];
        float v1 = xb[(size_t)(l + 1) * D_];
        float v2 = xb[(size_t)(l + 2) * D_];
        float v3 = xb[(size_t)(l + 3) * D_];
        s += v0 + v1 + v2 + v3;
        m = fmaxf(m, fmaxf(fmaxf(v0, v1), fmaxf(v2, v3)));
    }
    ps[grp][t] = s;
    pm[grp][t] = m;
    __syncthreads();
    if (grp == 0) {
        float ss = ps[0][t] + ps[1][t] + ps[2][t] + ps[3][t];
        float mm = fmaxf(fmaxf(pm[0][t], pm[1][t]), fmaxf(pm[2][t], pm[3][t]));
        sp[t] = (ss * (1.f / L_LEN) + mm) * 0.5f;
    }
    __syncthreads();
    if (tid < 256) {
        float acc = pb[tid];
        for (int d = 0; d < 256; ++d) acc += sp[d] * pw[tid * 256 + d];
        s1[tid] = geluf(acc);
    }
    __syncthreads();
    if (tid < 128) {
        float a = c1b[tid];
        for (int d = 0; d < 256; ++d) a += s1[d] * c1w[tid * 256 + d];
        s2[tid] = geluf(a);
    }
    __syncthreads();
    if (tid < 2) {
        float a = c2b[tid];
        for (int d = 0; d < 128; ++d) a += s2[d] * c2w[tid * 128 + d];
        out[b * NC_ + tid] = a;
    }
}

extern "C" void kernel_launch(void* const* d_in, const int* in_sizes, int n_in,
                              void* d_out, int out_size, void* d_ws, size_t ws_size,
                              hipStream_t stream) {
    const int* ids    = (const int*)d_in[0];
    const float* emb  = (const float*)d_in[1];
    const float* pos  = (const float*)d_in[2];
    const float* Wins = (const float*)d_in[3];
    const float* cw   = (const float*)d_in[4];
    const float* cb   = (const float*)d_in[5];
    const float* dtb  = (const float*)d_in[6];
    const float* Alog = (const float*)d_in[7];
    const float* Dpar = (const float*)d_in[8];
    const float* nw   = (const float*)d_in[9];
    const float* Wout = (const float*)d_in[10];
    const float* pw   = (const float*)d_in[11];
    const float* pb   = (const float*)d_in[12];
    const float* c1w  = (const float*)d_in[13];
    const float* c1b  = (const float*)d_in[14];
    const float* c2w  = (const float*)d_in[15];
    const float* c2b  = (const float*)d_in[16];
    float* out = (float*)d_out;

    const int NWIN = NL_ * DPROJ_ * D_;   // 1187840
    const int NWOUT = NL_ * D_ * DIN_;    // 524288
    const int NG = 1048576;               // 2048*512

    float* ws = (float*)d_ws;
    float* x      = ws;                 // 524288
    float* zx     = x + 524288;         // 2375680
    float* y      = zx + 2375680;       // 1048576
    float* Sbuf   = y + 1048576;        // 1048576
    float* Ctil   = Sbuf + 1048576;     // 1048576
    float* decay  = Ctil + 1048576;     // 256
    float* rowssq = decay + 256;        // 2048
    unsigned short* winh = (unsigned short*)(rowssq + 2048);
    unsigned short* winl = winh + NWIN;
    unsigned short* woh  = winl + NWIN;
    unsigned short* wol  = woh + NWOUT;
    unsigned short* gh   = wol + NWOUT;
    unsigned short* gl   = gh + NG;

    k_w2bf2<<<(NWIN + NWOUT + 255) / 256, 256, 0, stream>>>(
        Wins, Wout, nw, winh, winl, woh, wol, NWIN, NWIN + NWOUT);
    k_embed<<<2048, 256, 0, stream>>>(ids, emb, pos, x, 524288);
    for (int i = 0; i < NL_; ++i) {
        size_t wo_in = (size_t)i * DPROJ_ * D_;
        size_t wo_out = (size_t)i * D_ * DIN_;
        gemm_in<<<dim3(19, 32), 256, 0, stream>>>(
            x, winh + wo_in, winl + wo_in, zx, 2048, DPROJ_, D_);
        k_ssmA<<<dim3(NCH_, 16), 256, 0, stream>>>(
            zx, cw + (size_t)i * CONVDIM_ * 4, cb + (size_t)i * CONVDIM_,
            dtb + i * H_, Alog + i * H_, Dpar + i * H_, Sbuf, decay, Ctil, y, rowssq);
        k_inter<<<dim3(NCH_, 16), 256, 0, stream>>>(Sbuf, Ctil, decay, zx, y, gh, gl, rowssq);
        gemm_outs<<<dim3(4, 16, 8), 256, 0, stream>>>(
            gh, gl, rowssq, woh + wo_out, wol + wo_out, x);
    }
    k_poolhead<<<2, 1024, 0, stream>>>(x, pw, pb, c1w, c1b, c2w, c2b, out);
}

// Round 16
// 372.994 us; speedup vs baseline: 1.1260x; 1.1260x over previous
//
#include <hip/hip_runtime.h>
#include <math.h>

#define D_ 256
#define NL_ 4
#define NC_ 2
#define L_LEN 1024
#define NSTATE_ 64
#define DIN_ 512
#define H_ 8
#define P_ 64
#define CONVDIM_ 640
#define DPROJ_ 1160
#define EPS_ 1e-5f
#define NCH_ 16

typedef __attribute__((ext_vector_type(8))) short short8;
typedef __attribute__((ext_vector_type(4))) float f32x4;
typedef __attribute__((ext_vector_type(4))) unsigned short us4;

__device__ __forceinline__ float siluf(float x) { return x / (1.f + __expf(-x)); }
__device__ __forceinline__ float geluf(float x) { return 0.5f * x * (1.f + erff(x * 0.70710678118654752f)); }
__device__ __forceinline__ unsigned short f2bf(float f) {
    unsigned u = __float_as_uint(f);
    u += 0x7FFFu + ((u >> 16) & 1u);
    return (unsigned short)(u >> 16);
}
__device__ __forceinline__ float bf2f(unsigned short h) {
    return __uint_as_float(((unsigned)h) << 16);
}

// x[b,l,d] = emb[ids[b,l], d] + pos[l, d]
__global__ void k_embed(const int* __restrict__ ids, const float* __restrict__ emb,
                        const float* __restrict__ pos, float* __restrict__ x, int total) {
    int i = blockIdx.x * blockDim.x + threadIdx.x;
    if (i >= total) return;
    int d = i & (D_ - 1);
    int bl = i >> 8;
    int l = bl & (L_LEN - 1);
    x[i] = emb[ids[bl] * D_ + d] + pos[l * D_ + d];
}

// split Win and (Wout * nw) into bf16 hi/lo planes
__global__ void k_w2bf2(const float* __restrict__ Wi, const float* __restrict__ Wo,
                        const float* __restrict__ nw,
                        unsigned short* __restrict__ wih, unsigned short* __restrict__ wil,
                        unsigned short* __restrict__ woh, unsigned short* __restrict__ wol,
                        int nin, int ntot) {
    int i = blockIdx.x * blockDim.x + threadIdx.x;
    if (i >= ntot) return;
    if (i < nin) {
        float f = Wi[i];
        unsigned short h = f2bf(f);
        wih[i] = h;
        wil[i] = f2bf(f - bf2f(h));
    } else {
        int j = i - nin;
        int layer = j / (D_ * DIN_);
        int k = j % DIN_;
        float f = Wo[j] * nw[layer * DIN_ + k];
        unsigned short h = f2bf(f);
        woh[j] = h;
        wol[j] = f2bf(f - bf2f(h));
    }
}

// in-proj: zx[M,N] = x[M,K] @ Win^T; A f32 (split inline), B pre-split bf16.
// BM=128, BN=64, BK=32; grid (19, 16); K=256.  (R14-proven shape)
__global__ void __launch_bounds__(256) gemm_in(const float* __restrict__ A,
        const unsigned short* __restrict__ Bhi, const unsigned short* __restrict__ Blo,
        float* __restrict__ C, int M, int N, int K) {
    __shared__ __align__(16) unsigned short Ah[128 * 40];
    __shared__ __align__(16) unsigned short Al[128 * 40];
    __shared__ __align__(16) unsigned short Bh[64 * 40];
    __shared__ __align__(16) unsigned short Bl[64 * 40];
    const int tid = threadIdx.x;
    const int col0 = blockIdx.x * 64;
    const int row0 = blockIdx.y * 128;

    const int sar = tid >> 1, sas = (tid & 1) * 16;
    const int sbr = tid >> 2, sbs = (tid & 3) * 8;
    const bool bok = (col0 + sbr) < N;
    const float* aptr = A + (size_t)(row0 + sar) * K + sas;
    const unsigned short* bhptr = Bhi + (size_t)(col0 + sbr) * K + sbs;
    const unsigned short* blptr = Blo + (size_t)(col0 + sbr) * K + sbs;

    float4 pa[4];
    short8 pbh = {0, 0, 0, 0, 0, 0, 0, 0}, pbl = {0, 0, 0, 0, 0, 0, 0, 0};
#pragma unroll
    for (int i = 0; i < 4; ++i) pa[i] = *(const float4*)(aptr + i * 4);
    if (bok) {
        pbh = *(const short8*)bhptr;
        pbl = *(const short8*)blptr;
    }

    const int wave = tid >> 6, lane = tid & 63;
    const int lq = lane >> 4, lm = lane & 15;
    f32x4 acc[2][4] = {};
    const int nsteps = K >> 5;
    for (int s = 0; s < nsteps; ++s) {
        __syncthreads();
#pragma unroll
        for (int i = 0; i < 4; ++i) {
            float4 f = pa[i];
            unsigned short h0 = f2bf(f.x), h1 = f2bf(f.y), h2 = f2bf(f.z), h3 = f2bf(f.w);
            us4 hv = {h0, h1, h2, h3};
            us4 lv = {f2bf(f.x - bf2f(h0)), f2bf(f.y - bf2f(h1)),
                      f2bf(f.z - bf2f(h2)), f2bf(f.w - bf2f(h3))};
            *(us4*)&Ah[sar * 40 + sas + i * 4] = hv;
            *(us4*)&Al[sar * 40 + sas + i * 4] = lv;
        }
        *(short8*)&Bh[sbr * 40 + sbs] = pbh;
        *(short8*)&Bl[sbr * 40 + sbs] = pbl;
        __syncthreads();
        if (s + 1 < nsteps) {
            int ko = (s + 1) * 32;
#pragma unroll
            for (int i = 0; i < 4; ++i) pa[i] = *(const float4*)(aptr + ko + i * 4);
            if (bok) {
                pbh = *(const short8*)(bhptr + ko);
                pbl = *(const short8*)(blptr + ko);
            }
        }
        short8 bh[4], bl[4];
#pragma unroll
        for (int ct = 0; ct < 4; ++ct) {
            bh[ct] = *(const short8*)&Bh[(ct * 16 + lm) * 40 + lq * 8];
            bl[ct] = *(const short8*)&Bl[(ct * 16 + lm) * 40 + lq * 8];
        }
#pragma unroll
        for (int rt = 0; rt < 2; ++rt) {
            short8 ah = *(const short8*)&Ah[(wave * 32 + rt * 16 + lm) * 40 + lq * 8];
            short8 al = *(const short8*)&Al[(wave * 32 + rt * 16 + lm) * 40 + lq * 8];
#pragma unroll
            for (int ct = 0; ct < 4; ++ct) {
                acc[rt][ct] = __builtin_amdgcn_mfma_f32_16x16x32_bf16(ah, bh[ct], acc[rt][ct], 0, 0, 0);
                acc[rt][ct] = __builtin_amdgcn_mfma_f32_16x16x32_bf16(ah, bl[ct], acc[rt][ct], 0, 0, 0);
                acc[rt][ct] = __builtin_amdgcn_mfma_f32_16x16x32_bf16(al, bh[ct], acc[rt][ct], 0, 0, 0);
            }
        }
    }
#pragma unroll
    for (int rt = 0; rt < 2; ++rt) {
#pragma unroll
        for (int ct = 0; ct < 4; ++ct) {
            int col = col0 + ct * 16 + lm;
            if (col >= N) continue;
            int rbase = row0 + wave * 32 + rt * 16 + lq * 4;
#pragma unroll
            for (int reg = 0; reg < 4; ++reg) {
                C[(size_t)(rbase + reg) * N + col] = acc[rt][ct][reg];
            }
        }
    }
}

// out-proj: x[m][n] += sc[m] * sum_k g[m][k]*(W*nw)[n][k]; split-K 4 (R14-proven).
// grid (4, 16, 4): BN=64, BM=128, kchunk=128.
__global__ void __launch_bounds__(256) gemm_outs(const unsigned short* __restrict__ Ghg,
        const unsigned short* __restrict__ Glg, const float* __restrict__ rowssq,
        const unsigned short* __restrict__ Bhi, const unsigned short* __restrict__ Blo,
        float* __restrict__ x) {
    __shared__ __align__(16) unsigned short Ah[128 * 40];
    __shared__ __align__(16) unsigned short Al[128 * 40];
    __shared__ __align__(16) unsigned short Bh[64 * 40];
    __shared__ __align__(16) unsigned short Bl[64 * 40];
    const int tid = threadIdx.x;
    const int col0 = blockIdx.x * 64;
    const int row0 = blockIdx.y * 128;
    const int kbase = blockIdx.z * 128;
    const int sar = tid >> 1, sas = (tid & 1) * 16;
    const int sbr = tid >> 2, sbs = (tid & 3) * 8;
    const unsigned short* ahptr = Ghg + (size_t)(row0 + sar) * DIN_ + kbase + sas;
    const unsigned short* alptr = Glg + (size_t)(row0 + sar) * DIN_ + kbase + sas;
    const unsigned short* bhptr = Bhi + (size_t)(col0 + sbr) * DIN_ + kbase + sbs;
    const unsigned short* blptr = Blo + (size_t)(col0 + sbr) * DIN_ + kbase + sbs;

    short8 pah0 = *(const short8*)ahptr, pah1 = *(const short8*)(ahptr + 8);
    short8 pal0 = *(const short8*)alptr, pal1 = *(const short8*)(alptr + 8);
    short8 pbh = *(const short8*)bhptr, pbl = *(const short8*)blptr;

    const int wave = tid >> 6, lane = tid & 63;
    const int lq = lane >> 4, lm = lane & 15;
    f32x4 acc[2][4] = {};
    for (int s = 0; s < 4; ++s) {
        __syncthreads();
        *(short8*)&Ah[sar * 40 + sas] = pah0;
        *(short8*)&Ah[sar * 40 + sas + 8] = pah1;
        *(short8*)&Al[sar * 40 + sas] = pal0;
        *(short8*)&Al[sar * 40 + sas + 8] = pal1;
        *(short8*)&Bh[sbr * 40 + sbs] = pbh;
        *(short8*)&Bl[sbr * 40 + sbs] = pbl;
        __syncthreads();
        if (s + 1 < 4) {
            int ko = (s + 1) * 32;
            pah0 = *(const short8*)(ahptr + ko);
            pah1 = *(const short8*)(ahptr + ko + 8);
            pal0 = *(const short8*)(alptr + ko);
            pal1 = *(const short8*)(alptr + ko + 8);
            pbh = *(const short8*)(bhptr + ko);
            pbl = *(const short8*)(blptr + ko);
        }
        short8 bh[4], bl[4];
#pragma unroll
        for (int ct = 0; ct < 4; ++ct) {
            bh[ct] = *(const short8*)&Bh[(ct * 16 + lm) * 40 + lq * 8];
            bl[ct] = *(const short8*)&Bl[(ct * 16 + lm) * 40 + lq * 8];
        }
#pragma unroll
        for (int rt = 0; rt < 2; ++rt) {
            short8 ah = *(const short8*)&Ah[(wave * 32 + rt * 16 + lm) * 40 + lq * 8];
            short8 al = *(const short8*)&Al[(wave * 32 + rt * 16 + lm) * 40 + lq * 8];
#pragma unroll
            for (int ct = 0; ct < 4; ++ct) {
                acc[rt][ct] = __builtin_amdgcn_mfma_f32_16x16x32_bf16(ah, bh[ct], acc[rt][ct], 0, 0, 0);
                acc[rt][ct] = __builtin_amdgcn_mfma_f32_16x16x32_bf16(ah, bl[ct], acc[rt][ct], 0, 0, 0);
                acc[rt][ct] = __builtin_amdgcn_mfma_f32_16x16x32_bf16(al, bh[ct], acc[rt][ct], 0, 0, 0);
            }
        }
    }
#pragma unroll
    for (int rt = 0; rt < 2; ++rt) {
        int rbase = row0 + wave * 32 + rt * 16 + lq * 4;
        float sc[4];
#pragma unroll
        for (int reg = 0; reg < 4; ++reg)
            sc[reg] = rsqrtf(rowssq[rbase + reg] * (1.f / DIN_) + EPS_);
#pragma unroll
        for (int ct = 0; ct < 4; ++ct) {
            int col = col0 + ct * 16 + lm;
#pragma unroll
            for (int reg = 0; reg < 4; ++reg) {
                atomicAdd(&x[(size_t)(rbase + reg) * D_ + col], sc[reg] * acc[rt][ct][reg]);
            }
        }
    }
}

// Fused SSM: 512 threads — 8 waves stage (conv, Ctil), compute phases keep the
// R9-proven 4x4 micro on tid<256. Barriers outside guards.
__global__ void __launch_bounds__(512) k_ssmA(const float* __restrict__ zx,
        const float* __restrict__ cw, const float* __restrict__ cb,
        const float* __restrict__ dtbias, const float* __restrict__ Alog,
        const float* __restrict__ Dp,
        float* __restrict__ Sbuf, float* __restrict__ decay,
        float* __restrict__ Ctil, float* __restrict__ y, float* __restrict__ rowssq) {
    __shared__ float U[64][65];
    __shared__ float V[64][65];
    __shared__ float W[64][65];
    __shared__ float sdt[64], cs[64], wj[64];
    const int c = blockIdx.x, bh = blockIdx.y;
    const int b = bh >> 3, h = bh & 7;
    const int l0 = c << 6;
    const int tid = threadIdx.x, wid8 = tid >> 6, lane = tid & 63;

    if (h == 0 && tid < 64) rowssq[b * L_LEN + l0 + tid] = 0.f;

    const int chx = h * P_ + lane;
    const int chb = DIN_ + lane;
    const int chc = DIN_ + NSTATE_ + lane;
    float wx0 = cw[chx * 4], wx1 = cw[chx * 4 + 1], wx2 = cw[chx * 4 + 2], wx3 = cw[chx * 4 + 3];
    float wb0 = cw[chb * 4], wb1 = cw[chb * 4 + 1], wb2 = cw[chb * 4 + 2], wb3 = cw[chb * 4 + 3];
    float wc0 = cw[chc * 4], wc1 = cw[chc * 4 + 1], wc2 = cw[chc * 4 + 2], wc3 = cw[chc * 4 + 3];
    float bx = cb[chx], bb = cb[chb], bc = cb[chc];

    // conv staging: 8 waves, 8 rows each
    for (int r = 0; r < 64; r += 8) {
        int j = r + wid8;
        int l = l0 + j;
        float ax = bx, ab = bb, ac = bc;
#pragma unroll
        for (int k = 0; k < 4; ++k) {
            int t = l - 3 + k;
            if (t >= 0) {
                const float* row = zx + (size_t)(b * L_LEN + t) * DPROJ_;
                float wxk = (k == 0) ? wx0 : (k == 1) ? wx1 : (k == 2) ? wx2 : wx3;
                float wbk = (k == 0) ? wb0 : (k == 1) ? wb1 : (k == 2) ? wb2 : wb3;
                float wck = (k == 0) ? wc0 : (k == 1) ? wc1 : (k == 2) ? wc2 : wc3;
                ax += wxk * row[DIN_ + chx];
                ab += wbk * row[DIN_ + chb];
                ac += wck * row[DIN_ + chc];
            }
        }
        U[j][lane] = siluf(ax);
        V[j][lane] = siluf(ab);
        W[j][lane] = siluf(ac);
    }
    if (tid < 64) {
        float xv = zx[(size_t)(b * L_LEN + l0 + tid) * DPROJ_ + (DPROJ_ - H_) + h] + dtbias[h];
        float sp = fmaxf(xv, 0.f) + log1pf(__expf(-fabsf(xv)));
        sdt[tid] = sp;
        float v = sp * (-__expf(Alog[h]));
#pragma unroll
        for (int off = 1; off < 64; off <<= 1) {
            float t = __shfl_up(v, off, 64);
            if (tid >= off) v += t;
        }
        cs[tid] = v;
        float tot = __shfl(v, 63, 64);
        wj[tid] = __expf(tot - v) * sp;
        if (tid == 63) decay[bh * NCH_ + c] = __expf(tot);
    }
    __syncthreads();

    const int t4 = (tid & 15) * 4;
    const int r4 = ((tid >> 4) & 15) * 4;
    const size_t sbase = (size_t)(bh * NCH_ + c) * 4096;

    // S_local (tid<256, 4x4 micro)
    if (tid < 256) {
        float acc[4][4] = {};
        for (int j = 0; j < 64; ++j) {
            float w = wj[j];
            float4 xv = *(const float4*)&U[j][r4];
            float4 bv = *(const float4*)&V[j][t4];
            float xw[4] = {xv.x * w, xv.y * w, xv.z * w, xv.w * w};
#pragma unroll
            for (int ii = 0; ii < 4; ++ii) {
                acc[ii][0] += xw[ii] * bv.x;
                acc[ii][1] += xw[ii] * bv.y;
                acc[ii][2] += xw[ii] * bv.z;
                acc[ii][3] += xw[ii] * bv.w;
            }
        }
#pragma unroll
        for (int ii = 0; ii < 4; ++ii) {
            float4 v = {acc[ii][0], acc[ii][1], acc[ii][2], acc[ii][3]};
            *(float4*)&Sbuf[sbase + (size_t)(r4 + ii) * 64 + t4] = v;
        }
    }
    // Ctil (all 512 threads)
    for (int r = 0; r < 64; r += 8) {
        int ii = r + wid8;
        Ctil[sbase + ii * 64 + lane] = __expf(cs[ii]) * W[ii][lane];
    }
    // G + masked transpose (tid<256)
    float wt[4][4];
    if (tid < 256) {
        float g[4][4] = {};
        for (int ng = 0; ng < 64; ng += 4) {
            float4 cf[4], bf[4];
#pragma unroll
            for (int ii = 0; ii < 4; ++ii) cf[ii] = *(const float4*)&W[r4 + ii][ng];
#pragma unroll
            for (int jj = 0; jj < 4; ++jj) bf[jj] = *(const float4*)&V[t4 + jj][ng];
#pragma unroll
            for (int ii = 0; ii < 4; ++ii)
#pragma unroll
                for (int jj = 0; jj < 4; ++jj)
                    g[ii][jj] += cf[ii].x * bf[jj].x + cf[ii].y * bf[jj].y +
                                 cf[ii].z * bf[jj].z + cf[ii].w * bf[jj].w;
        }
#pragma unroll
        for (int ii = 0; ii < 4; ++ii) {
            int i = r4 + ii;
            float csi = cs[i];
#pragma unroll
            for (int jj = 0; jj < 4; ++jj) {
                int j = t4 + jj;
                wt[ii][jj] = (j <= i) ? __expf(fminf(csi - cs[j], 0.f)) * sdt[j] * g[ii][jj] : 0.f;
            }
        }
    }
    __syncthreads();
    if (tid < 256) {
#pragma unroll
        for (int jj = 0; jj < 4; ++jj) {
            float4 v = {wt[0][jj], wt[1][jj], wt[2][jj], wt[3][jj]};
            *(float4*)&V[t4 + jj][r4] = v;
        }
    }
    __syncthreads();
    // intra Y (tid<256)
    if (tid < 256) {
        float acc[4][4] = {};
        for (int j = 0; j < 64; ++j) {
            float4 wv = *(const float4*)&V[j][r4];
            float4 xv = *(const float4*)&U[j][t4];
            float ws[4] = {wv.x, wv.y, wv.z, wv.w};
#pragma unroll
            for (int ii = 0; ii < 4; ++ii) {
                acc[ii][0] += ws[ii] * xv.x;
                acc[ii][1] += ws[ii] * xv.y;
                acc[ii][2] += ws[ii] * xv.z;
                acc[ii][3] += ws[ii] * xv.w;
            }
        }
        float Dh = Dp[h];
#pragma unroll
        for (int ii = 0; ii < 4; ++ii) {
            float4 xv = *(const float4*)&U[r4 + ii][t4];
            float4 v = {acc[ii][0] + Dh * xv.x, acc[ii][1] + Dh * xv.y,
                        acc[ii][2] + Dh * xv.z, acc[ii][3] + Dh * xv.w};
            *(float4*)&y[(size_t)(b * L_LEN + l0 + r4 + ii) * DIN_ + h * P_ + t4] = v;
        }
    }
}

// inter-chunk + prefix scan + gating, 512 threads (staging on 8 waves, compute on 4).
__global__ void __launch_bounds__(512) k_inter(const float* __restrict__ Sbuf,
        const float* __restrict__ Ctil, const float* __restrict__ decay,
        const float* __restrict__ zx, const float* __restrict__ y,
        unsigned short* __restrict__ gh, unsigned short* __restrict__ gl,
        float* __restrict__ rowssq) {
    __shared__ float Sm[64][65];
    __shared__ float Cm[64][65];
    const int c = blockIdx.x, bh = blockIdx.y;
    const int b = bh >> 3, h = bh & 7;
    const int l0 = c << 6;
    const int tid = threadIdx.x, wid8 = tid >> 6, lane = tid & 63;
    const size_t bhbase = (size_t)bh * NCH_ * 4096;

    float dec[NCH_];
#pragma unroll
    for (int k = 0; k < NCH_; ++k) dec[k] = decay[bh * NCH_ + k];

    // prefix reconstruction: 512 threads, 8 elements each
    float acc8[8] = {};
    float wgt = 1.f;
    for (int cp = c - 1; cp >= 0; --cp) {
        const float* src = Sbuf + bhbase + (size_t)cp * 4096;
#pragma unroll
        for (int i = 0; i < 8; ++i) acc8[i] += wgt * src[i * 512 + tid];
        wgt *= dec[cp];
    }
#pragma unroll
    for (int i = 0; i < 8; ++i) Sm[i * 8 + wid8][lane] = acc8[i];

    const size_t base = bhbase + (size_t)c * 4096;
    for (int r = 0; r < 64; r += 8) {
        int pp = r + wid8;
        Cm[pp][lane] = Ctil[base + pp * 64 + lane];
    }
    __syncthreads();
    const int t4 = (tid & 15) * 4;
    const int r4 = ((tid >> 4) & 15) * 4;
    if (tid < 256) {
        float acc[4][4] = {};
        if (c > 0) {
            for (int ng = 0; ng < 64; ng += 4) {
                float4 cf[4], sf[4];
#pragma unroll
                for (int ii = 0; ii < 4; ++ii) cf[ii] = *(const float4*)&Cm[r4 + ii][ng];
#pragma unroll
                for (int pp = 0; pp < 4; ++pp) sf[pp] = *(const float4*)&Sm[t4 + pp][ng];
#pragma unroll
                for (int ii = 0; ii < 4; ++ii)
#pragma unroll
                    for (int pp = 0; pp < 4; ++pp)
                        acc[ii][pp] += cf[ii].x * sf[pp].x + cf[ii].y * sf[pp].y +
                                       cf[ii].z * sf[pp].z + cf[ii].w * sf[pp].w;
            }
        }
        float ssq[4];
#pragma unroll
        for (int ii = 0; ii < 4; ++ii) {
            int row = b * L_LEN + l0 + r4 + ii;
            const float* yr = &y[(size_t)row * DIN_ + h * P_ + t4];
            const float* zr = &zx[(size_t)row * DPROJ_ + h * P_ + t4];
            float4 v = *(const float4*)yr;
            float4 z = *(const float4*)zr;
            v.x = (v.x + acc[ii][0]) * siluf(z.x);
            v.y = (v.y + acc[ii][1]) * siluf(z.y);
            v.z = (v.z + acc[ii][2]) * siluf(z.z);
            v.w = (v.w + acc[ii][3]) * siluf(z.w);
            unsigned short h0 = f2bf(v.x), h1 = f2bf(v.y), h2 = f2bf(v.z), h3 = f2bf(v.w);
            us4 hv = {h0, h1, h2, h3};
            us4 lv = {f2bf(v.x - bf2f(h0)), f2bf(v.y - bf2f(h1)),
                      f2bf(v.z - bf2f(h2)), f2bf(v.w - bf2f(h3))};
            *(us4*)&gh[(size_t)row * DIN_ + h * P_ + t4] = hv;
            *(us4*)&gl[(size_t)row * DIN_ + h * P_ + t4] = lv;
            ssq[ii] = v.x * v.x + v.y * v.y + v.z * v.z + v.w * v.w;
        }
#pragma unroll
        for (int o = 1; o < 16; o <<= 1) {
#pragma unroll
            for (int ii = 0; ii < 4; ++ii) ssq[ii] += __shfl_xor(ssq[ii], o, 64);
        }
        if ((tid & 15) == 0) {
#pragma unroll
            for (int ii = 0; ii < 4; ++ii)
                atomicAdd(&rowssq[b * L_LEN + l0 + r4 + ii], ssq[ii]);
        }
    }
}

// pooling + classifier head, one block per batch, 1024 threads
__global__ void __launch_bounds__(1024) k_poolhead(const float* __restrict__ x,
                           const float* __restrict__ pw, const float* __restrict__ pb,
                           const float* __restrict__ c1w, const float* __restrict__ c1b,
                           const float* __restrict__ c2w, const float* __restrict__ c2b,
                           float* __restrict__ out) {
    __shared__ float ps[4][256], pm[4][256];
    __shared__ float sp[256], s1[256], s2[128];
    int b = blockIdx.x, tid = threadIdx.x;
    int t = tid & 255, grp = tid >> 8;
    const float* xb = x + (size_t)b * L_LEN * D_ + (size_t)grp * 256 * D_ + t;
    float s = 0.f, m = -INFINITY;
    for (int l = 0; l < 256; l += 4) {
        float v0 = xb[(size_t)l * D_];
        float v1 = xb[(size_t)(l + 1) * D_];
        float v2 = xb[(size_t)(l + 2) * D_];
        float v3 = xb[(size_t)(l + 3) * D_];
        s += v0 + v1 + v2 + v3;
        m = fmaxf(m, fmaxf(fmaxf(v0, v1), fmaxf(v2, v3)));
    }
    ps[grp][t] = s;
    pm[grp][t] = m;
    __syncthreads();
    if (grp == 0) {
        float ss = ps[0][t] + ps[1][t] + ps[2][t] + ps[3][t];
        float mm = fmaxf(fmaxf(pm[0][t], pm[1][t]), fmaxf(pm[2][t], pm[3][t]));
        sp[t] = (ss * (1.f / L_LEN) + mm) * 0.5f;
    }
    __syncthreads();
    if (tid < 256) {
        float acc = pb[tid];
        for (int d = 0; d < 256; ++d) acc += sp[d] * pw[tid * 256 + d];
        s1[tid] = geluf(acc);
    }
    __syncthreads();
    if (tid < 128) {
        float a = c1b[tid];
        for (int d = 0; d < 256; ++d) a += s1[d] * c1w[tid * 256 + d];
        s2[tid] = geluf(a);
    }
    __syncthreads();
    if (tid < 2) {
        float a = c2b[tid];
        for (int d = 0; d < 128; ++d) a += s2[d] * c2w[tid * 128 + d];
        out[b * NC_ + tid] = a;
    }
}

extern "C" void kernel_launch(void* const* d_in, const int* in_sizes, int n_in,
                              void* d_out, int out_size, void* d_ws, size_t ws_size,
                              hipStream_t stream) {
    const int* ids    = (const int*)d_in[0];
    const float* emb  = (const float*)d_in[1];
    const float* pos  = (const float*)d_in[2];
    const float* Wins = (const float*)d_in[3];
    const float* cw   = (const float*)d_in[4];
    const float* cb   = (const float*)d_in[5];
    const float* dtb  = (const float*)d_in[6];
    const float* Alog = (const float*)d_in[7];
    const float* Dpar = (const float*)d_in[8];
    const float* nw   = (const float*)d_in[9];
    const float* Wout = (const float*)d_in[10];
    const float* pw   = (const float*)d_in[11];
    const float* pb   = (const float*)d_in[12];
    const float* c1w  = (const float*)d_in[13];
    const float* c1b  = (const float*)d_in[14];
    const float* c2w  = (const float*)d_in[15];
    const float* c2b  = (const float*)d_in[16];
    float* out = (float*)d_out;

    const int NWIN = NL_ * DPROJ_ * D_;   // 1187840
    const int NWOUT = NL_ * D_ * DIN_;    // 524288
    const int NG = 1048576;               // 2048*512

    float* ws = (float*)d_ws;
    float* x      = ws;                 // 524288
    float* zx     = x + 524288;         // 2375680
    float* y      = zx + 2375680;       // 1048576
    float* Sbuf   = y + 1048576;        // 1048576
    float* Ctil   = Sbuf + 1048576;     // 1048576
    float* decay  = Ctil + 1048576;     // 256
    float* rowssq = decay + 256;        // 2048
    unsigned short* winh = (unsigned short*)(rowssq + 2048);
    unsigned short* winl = winh + NWIN;
    unsigned short* woh  = winl + NWIN;
    unsigned short* wol  = woh + NWOUT;
    unsigned short* gh   = wol + NWOUT;
    unsigned short* gl   = gh + NG;

    k_w2bf2<<<(NWIN + NWOUT + 255) / 256, 256, 0, stream>>>(
        Wins, Wout, nw, winh, winl, woh, wol, NWIN, NWIN + NWOUT);
    k_embed<<<2048, 256, 0, stream>>>(ids, emb, pos, x, 524288);
    for (int i = 0; i < NL_; ++i) {
        size_t wo_in = (size_t)i * DPROJ_ * D_;
        size_t wo_out = (size_t)i * D_ * DIN_;
        gemm_in<<<dim3(19, 16), 256, 0, stream>>>(
            x, winh + wo_in, winl + wo_in, zx, 2048, DPROJ_, D_);
        k_ssmA<<<dim3(NCH_, 16), 512, 0, stream>>>(
            zx, cw + (size_t)i * CONVDIM_ * 4, cb + (size_t)i * CONVDIM_,
            dtb + i * H_, Alog + i * H_, Dpar + i * H_, Sbuf, decay, Ctil, y, rowssq);
        k_inter<<<dim3(NCH_, 16), 512, 0, stream>>>(Sbuf, Ctil, decay, zx, y, gh, gl, rowssq);
        gemm_outs<<<dim3(4, 16, 4), 256, 0, stream>>>(
            gh, gl, rowssq, woh + wo_out, wol + wo_out, x);
    }
    k_poolhead<<<2, 1024, 0, stream>>>(x, pw, pb, c1w, c1b, c2w, c2b, out);
}